// Round 21
// baseline (163.228 us; speedup 1.0000x reference)
//
#include <hip/hip_runtime.h>
#include <hip/hip_fp16.h>
#include <math.h>

#define HW 512
#define MASK 511
#define IMG (512*512)
#define NSTEP 16
#define NSLICE 17

#define TR 85             // tile rows: [Y0-10, Y0+75); row 84 only feeds zero-weights
#define TSTR 104          // ushort stride/row: 13 granules (odd -> uniform banks)
#define WSB_OFF 32        // ushort offset of B-frag table in ws

typedef _Float16 half_t;
typedef __attribute__((ext_vector_type(8))) _Float16 f16x8;
typedef __attribute__((ext_vector_type(4))) float f32x4;

// T19 sched_group_barrier masks (LLVM SchedGroupMask)
#define SGB(mask, n) __builtin_amdgcn_sched_group_barrier((mask), (n), 0)
#define M_MFMA 0x8
#define M_DSRD 0x100
#define M_VMRD 0x20

// B-frags (2-row Toeplitz, 16x16x32, single fp16 W): frag f = p*3 + u.
//   p: dy-pair (rows 2p, 2p+1), u: window class (r = 16u).
// lane l, elem j -> k = 8*(l>>4)+j, n = l&15.
//   k<16  -> dy = 2p,   tap d = 16u + k      - n - 6
//   k>=16 -> dy = 2p+1, tap d = 16u + (k-16) - n - 6
// B = rne_fp16(W[dy][d]) if dy<=20 && 0<=d<=20 else 0.  A shares the
// (lane,j)->k map, so any fixed HW k-permutation cancels.
__global__ void prep_kernel(const float* __restrict__ w1,
                            const float* __restrict__ w2,
                            const float* __restrict__ w3,
                            float* __restrict__ ws) {
    int tid = threadIdx.x;
    if (tid == 0) {
        // 1->10->1 MLP on nonneg scalar collapses: C = sum_o w3[o]*max(w2[o],0)
        float c = 0.f;
        for (int o = 0; o < 10; ++o) c += w3[o] * fmaxf(w2[o], 0.f);
        ws[0] = c;
    }
    half_t* wsb = (half_t*)((unsigned short*)ws + WSB_OFF);
    for (int u2 = tid; u2 < 33 * 512; u2 += blockDim.x) {
        int f = u2 >> 9, rem = u2 & 511, l = rem >> 3, j = rem & 7;
        int p = f / 3, rc = f % 3;
        int k = ((l >> 4) << 3) + j, n = l & 15;
        int dy = 2 * p + (k >= 16 ? 1 : 0);
        int d = 16 * rc + (k & 15) - n - 6;
        float wf = (dy <= 20 && d >= 0 && d <= 20) ? w1[dy * 21 + d] : 0.f;
        wsb[u2] = (half_t)wf;              // single rne fp16
    }
}

__global__ void copy_kernel(const float* __restrict__ x, float* __restrict__ out) {
    int i = blockIdx.x * blockDim.x + threadIdx.x;   // float4 index
    if (i < 8 * 65536) {
        const float4* in4 = (const float4*)x;
        float4* out4 = (float4*)out;
        int b = i >> 16;
        int off = i & 65535;
        out4[(size_t)b * (NSLICE * 65536) + off] = in4[i];
    }
}

__global__ __launch_bounds__(256, 2)
void step_kernel(const float* __restrict__ state_base,
                 float* __restrict__ out_base,
                 const float* __restrict__ ws,
                 int t) {
    __shared__ half_t tlh[TR * TSTR];   // x fp16 tile, 17680 B

    const int tid = threadIdx.x;
    const int lane = tid & 63, w = tid >> 6;          // 4 waves, 16x64 out each
    const int X0 = blockIdx.x * 64, Y0 = blockIdx.y * 64, b = blockIdx.z;

    const float* __restrict__ in  = state_base + (size_t)(b * NSLICE + (t - 1)) * IMG;
    float* __restrict__ outp      = out_base   + (size_t)(b * NSLICE + t) * IMG;

    // stage 85 x 96 fp32 -> fp16 tile; cols gx in [X0-16, X0+80)
    for (int u = tid; u < TR * 12; u += 256) {
        int r = u / 12, ch = u - r * 12;
        int gr = (Y0 + r - 10) & MASK;
        int gc = X0 + 8 * ch - 16;
        float4 a  = *(const float4*)&in[gr * HW + (gc & MASK)];
        float4 c2 = *(const float4*)&in[gr * HW + ((gc + 4) & MASK)];
        float v[8] = {a.x, a.y, a.z, a.w, c2.x, c2.y, c2.z, c2.w};
        f16x8 hh;
        #pragma unroll
        for (int q = 0; q < 8; ++q) hh[q] = (half_t)v[q];
        *(f16x8*)&tlh[r * TSTR + 8 * ch] = hh;
    }

    // prefetch fp32 residual centers (L2-hot) while staging drains
    const int gy0 = Y0 + 16 * w + (((lane >> 4) & 3) << 2);
    const int gxb = X0 + (lane & 15);
    float4 xv0, xv1, xv2, xv3;
    xv0.x = in[(gy0+0)*HW + gxb];      xv0.y = in[(gy0+1)*HW + gxb];
    xv0.z = in[(gy0+2)*HW + gxb];      xv0.w = in[(gy0+3)*HW + gxb];
    xv1.x = in[(gy0+0)*HW + gxb+16];   xv1.y = in[(gy0+1)*HW + gxb+16];
    xv1.z = in[(gy0+2)*HW + gxb+16];   xv1.w = in[(gy0+3)*HW + gxb+16];
    xv2.x = in[(gy0+0)*HW + gxb+32];   xv2.y = in[(gy0+1)*HW + gxb+32];
    xv2.z = in[(gy0+2)*HW + gxb+32];   xv2.w = in[(gy0+3)*HW + gxb+32];
    xv3.x = in[(gy0+0)*HW + gxb+48];   xv3.y = in[(gy0+1)*HW + gxb+48];
    xv3.z = in[(gy0+2)*HW + gxb+48];   xv3.w = in[(gy0+3)*HW + gxb+48];

    __syncthreads();

    const f16x8* bglob = (const f16x8*)((const unsigned short*)ws + WSB_OFF);
    // A-frag per-lane base: row = 16w + (lane&15) + (lane>>5), col = 8*((lane>>4)&1).
    const int abase = (16 * w + (lane & 15) + (lane >> 5)) * TSTR
                    + (((lane >> 4) & 1) << 3);

    f32x4 acc0 = {0.f,0.f,0.f,0.f}, acc1 = acc0, acc2 = acc0, acc3 = acc0;

    // double-buffered A (6 windows) and B (3 frags), static indices only
    f16x8 aX[6], aY[6];
    f16x8 bX[3], bY[3];    // [u]: window class

    auto LOADA = [&](f16x8 (&A)[6], int p) {
        const half_t* rp = &tlh[abase + 2 * p * TSTR];
        #pragma unroll
        for (int i = 0; i < 6; ++i) A[i] = *(const f16x8*)(rp + 16 * i);
    };
    auto LOADB = [&](f16x8 (&B)[3], int p) {
        const f16x8* nb = bglob + p * 192 + lane;
        #pragma unroll
        for (int i = 0; i < 3; ++i) B[i] = nb[i * 64];
    };
    auto MFMA12 = [&](const f16x8 (&A)[6], const f16x8 (&B)[3]) {
        acc0 = __builtin_amdgcn_mfma_f32_16x16x32_f16(A[0], B[0], acc0, 0,0,0);
        acc1 = __builtin_amdgcn_mfma_f32_16x16x32_f16(A[1], B[0], acc1, 0,0,0);
        acc2 = __builtin_amdgcn_mfma_f32_16x16x32_f16(A[2], B[0], acc2, 0,0,0);
        acc3 = __builtin_amdgcn_mfma_f32_16x16x32_f16(A[3], B[0], acc3, 0,0,0);
        acc0 = __builtin_amdgcn_mfma_f32_16x16x32_f16(A[1], B[1], acc0, 0,0,0);
        acc1 = __builtin_amdgcn_mfma_f32_16x16x32_f16(A[2], B[1], acc1, 0,0,0);
        acc2 = __builtin_amdgcn_mfma_f32_16x16x32_f16(A[3], B[1], acc2, 0,0,0);
        acc3 = __builtin_amdgcn_mfma_f32_16x16x32_f16(A[4], B[1], acc3, 0,0,0);
        acc0 = __builtin_amdgcn_mfma_f32_16x16x32_f16(A[2], B[2], acc0, 0,0,0);
        acc1 = __builtin_amdgcn_mfma_f32_16x16x32_f16(A[3], B[2], acc1, 0,0,0);
        acc2 = __builtin_amdgcn_mfma_f32_16x16x32_f16(A[4], B[2], acc2, 0,0,0);
        acc3 = __builtin_amdgcn_mfma_f32_16x16x32_f16(A[5], B[2], acc3, 0,0,0);
    };
    // T19 fine interleave: pin {DS 1, MFMA 2, DS 1, MFMA 2, VMEM 1} x3 per pair
    // so LDS / VMEM / matrix pipes are fed concurrently even in wave-lockstep.
    auto WEAVE = [&]() {
        #pragma unroll
        for (int g = 0; g < 3; ++g) {
            SGB(M_DSRD, 1); SGB(M_MFMA, 2);
            SGB(M_DSRD, 1); SGB(M_MFMA, 2);
            SGB(M_VMRD, 1);
        }
    };

    // prologue: pair 0 operands in flight
    LOADA(aX, 0);
    LOADB(bX, 0);

    // 11 pairs (dy 0..21; pair 10's second row hits zero weights).
    // No sched_barrier: one scheduling region, SGB pins the interleave.
    #define ST(p, AT, AN, BT, BN)                                     \
        do {                                                          \
            if ((p) < 10) {                                           \
                LOADA(AN, (p) + 1); LOADB(BN, (p) + 1);               \
                MFMA12(AT, BT);                                       \
                WEAVE();                                              \
            } else {                                                  \
                MFMA12(AT, BT);                                       \
                SGB(M_MFMA, 12);                                      \
            }                                                         \
        } while (0)

    ST( 0, aX, aY, bX, bY); ST( 1, aY, aX, bY, bX);
    ST( 2, aX, aY, bX, bY); ST( 3, aY, aX, bY, bX);
    ST( 4, aX, aY, bX, bY); ST( 5, aY, aX, bY, bX);
    ST( 6, aX, aY, bX, bY); ST( 7, aY, aX, bY, bX);
    ST( 8, aX, aY, bX, bY); ST( 9, aY, aX, bY, bX);
    ST(10, aX, aY, bX, bY);
    #undef ST

    // D layout: lane l, reg q -> row = (l>>4)*4 + q, col = l&15 (dtype-indep)
    const float C = ws[0];
    auto EPI = [&](const f32x4& a4v, const float4& xv, int j) {
        int gx = gxb + 16 * j;
        float cv[4] = {xv.x, xv.y, xv.z, xv.w};
        #pragma unroll
        for (int q = 0; q < 4; ++q) {
            int gy = gy0 + q;
            float a  = cv[q] + C * fmaxf(a4v[q], 0.f);
            float e  = __expf(2.f * fabsf(a));        // tanh(|a|) = 1 - 2/(e+1)
            float r  = 1.f - 2.f * __builtin_amdgcn_rcpf(e + 1.f);
            outp[gy * HW + gx] = copysignf(r, a);
        }
    };
    EPI(acc0, xv0, 0); EPI(acc1, xv1, 1); EPI(acc2, xv2, 2); EPI(acc3, xv3, 3);
}

extern "C" void kernel_launch(void* const* d_in, const int* in_sizes, int n_in,
                              void* d_out, int out_size, void* d_ws, size_t ws_size,
                              hipStream_t stream) {
    const float* x  = (const float*)d_in[0];
    const float* w1 = (const float*)d_in[1];
    const float* w2 = (const float*)d_in[2];
    const float* w3 = (const float*)d_in[3];
    float* out = (float*)d_out;
    float* ws  = (float*)d_ws;

    prep_kernel<<<1, 256, 0, stream>>>(w1, w2, w3, ws);
    copy_kernel<<<2048, 256, 0, stream>>>(x, out);

    dim3 grid(8, 8, 8);      // 512 blocks (64x64 out each) = 2/CU
    dim3 block(256);
    for (int t = 1; t <= NSTEP; ++t)
        step_kernel<<<grid, block, 0, stream>>>(out, out, ws, t);
}

// Round 22
// 158.966 us; speedup vs baseline: 1.0268x; 1.0268x over previous
//
#include <hip/hip_runtime.h>
#include <hip/hip_fp16.h>
#include <math.h>

#define HW 512
#define MASK 511
#define IMG (512*512)
#define NSTEP 16
#define NSLICE 17

#define TR 85             // tile rows: [Y0-10, Y0+75); row 84 only feeds zero-weights
#define TSTR 104          // ushort stride/row: 13 granules (odd -> uniform banks)
#define WSB_OFF 32        // ushort offset of B-frag table in ws

typedef _Float16 half_t;
typedef __attribute__((ext_vector_type(8))) _Float16 f16x8;
typedef __attribute__((ext_vector_type(4))) float f32x4;

#define SBAR() __builtin_amdgcn_sched_barrier(0)

// B-frags (2-row Toeplitz, 16x16x32, single fp16 W): frag f = p*3 + u.
//   p: dy-pair (rows 2p, 2p+1), u: window class (r = 16u).
// lane l, elem j -> k = 8*(l>>4)+j, n = l&15.
//   k<16  -> dy = 2p,   tap d = 16u + k      - n - 6
//   k>=16 -> dy = 2p+1, tap d = 16u + (k-16) - n - 6
// B = rne_fp16(W[dy][d]) if dy<=20 && 0<=d<=20 else 0.  A shares the
// (lane,j)->k map, so any fixed HW k-permutation cancels.
__global__ void prep_kernel(const float* __restrict__ w1,
                            const float* __restrict__ w2,
                            const float* __restrict__ w3,
                            float* __restrict__ ws) {
    int tid = threadIdx.x;
    if (tid == 0) {
        // 1->10->1 MLP on nonneg scalar collapses: C = sum_o w3[o]*max(w2[o],0)
        float c = 0.f;
        for (int o = 0; o < 10; ++o) c += w3[o] * fmaxf(w2[o], 0.f);
        ws[0] = c;
    }
    half_t* wsb = (half_t*)((unsigned short*)ws + WSB_OFF);
    for (int u2 = tid; u2 < 33 * 512; u2 += blockDim.x) {
        int f = u2 >> 9, rem = u2 & 511, l = rem >> 3, j = rem & 7;
        int p = f / 3, rc = f % 3;
        int k = ((l >> 4) << 3) + j, n = l & 15;
        int dy = 2 * p + (k >= 16 ? 1 : 0);
        int d = 16 * rc + (k & 15) - n - 6;
        float wf = (dy <= 20 && d >= 0 && d <= 20) ? w1[dy * 21 + d] : 0.f;
        wsb[u2] = (half_t)wf;              // single rne fp16
    }
}

__global__ void copy_kernel(const float* __restrict__ x, float* __restrict__ out) {
    int i = blockIdx.x * blockDim.x + threadIdx.x;   // float4 index
    if (i < 8 * 65536) {
        const float4* in4 = (const float4*)x;
        float4* out4 = (float4*)out;
        int b = i >> 16;
        int off = i & 65535;
        out4[(size_t)b * (NSLICE * 65536) + off] = in4[i];
    }
}

__global__ __launch_bounds__(256, 2)
void step_kernel(const float* __restrict__ state_base,
                 float* __restrict__ out_base,
                 const float* __restrict__ ws,
                 int t) {
    __shared__ half_t tlh[TR * TSTR];   // x fp16 tile, 17680 B

    const int tid = threadIdx.x;
    const int lane = tid & 63, w = tid >> 6;          // 4 waves, 16x64 out each
    const int X0 = blockIdx.x * 64, Y0 = blockIdx.y * 64, b = blockIdx.z;

    const float* __restrict__ in  = state_base + (size_t)(b * NSLICE + (t - 1)) * IMG;
    float* __restrict__ outp      = out_base   + (size_t)(b * NSLICE + t) * IMG;

    // stage 85 x 96 fp32 -> fp16 tile; cols gx in [X0-16, X0+80)
    for (int u = tid; u < TR * 12; u += 256) {
        int r = u / 12, ch = u - r * 12;
        int gr = (Y0 + r - 10) & MASK;
        int gc = X0 + 8 * ch - 16;
        float4 a  = *(const float4*)&in[gr * HW + (gc & MASK)];
        float4 c2 = *(const float4*)&in[gr * HW + ((gc + 4) & MASK)];
        float v[8] = {a.x, a.y, a.z, a.w, c2.x, c2.y, c2.z, c2.w};
        f16x8 hh;
        #pragma unroll
        for (int q = 0; q < 8; ++q) hh[q] = (half_t)v[q];
        *(f16x8*)&tlh[r * TSTR + 8 * ch] = hh;
    }

    // prefetch fp32 residual centers (L2-hot) while staging drains
    const int gy0 = Y0 + 16 * w + (((lane >> 4) & 3) << 2);
    const int gxb = X0 + (lane & 15);
    float4 xv0, xv1, xv2, xv3;
    xv0.x = in[(gy0+0)*HW + gxb];      xv0.y = in[(gy0+1)*HW + gxb];
    xv0.z = in[(gy0+2)*HW + gxb];      xv0.w = in[(gy0+3)*HW + gxb];
    xv1.x = in[(gy0+0)*HW + gxb+16];   xv1.y = in[(gy0+1)*HW + gxb+16];
    xv1.z = in[(gy0+2)*HW + gxb+16];   xv1.w = in[(gy0+3)*HW + gxb+16];
    xv2.x = in[(gy0+0)*HW + gxb+32];   xv2.y = in[(gy0+1)*HW + gxb+32];
    xv2.z = in[(gy0+2)*HW + gxb+32];   xv2.w = in[(gy0+3)*HW + gxb+32];
    xv3.x = in[(gy0+0)*HW + gxb+48];   xv3.y = in[(gy0+1)*HW + gxb+48];
    xv3.z = in[(gy0+2)*HW + gxb+48];   xv3.w = in[(gy0+3)*HW + gxb+48];

    __syncthreads();

    const f16x8* bglob = (const f16x8*)((const unsigned short*)ws + WSB_OFF);
    // A-frag per-lane base: row = 16w + (lane&15) + (lane>>5), col = 8*((lane>>4)&1).
    const int abase = (16 * w + (lane & 15) + (lane >> 5)) * TSTR
                    + (((lane >> 4) & 1) << 3);

    f32x4 acc0 = {0.f,0.f,0.f,0.f}, acc1 = acc0, acc2 = acc0, acc3 = acc0;

    // double-buffered A (6 windows) and B (3 frags), static indices only
    f16x8 aX[6], aY[6];
    f16x8 bX[3], bY[3];    // [u]: window class

    auto LOADA = [&](f16x8 (&A)[6], int p) {
        const half_t* rp = &tlh[abase + 2 * p * TSTR];
        #pragma unroll
        for (int i = 0; i < 6; ++i) A[i] = *(const f16x8*)(rp + 16 * i);
    };
    auto LOADB = [&](f16x8 (&B)[3], int p) {
        const f16x8* nb = bglob + p * 192 + lane;
        #pragma unroll
        for (int i = 0; i < 3; ++i) B[i] = nb[i * 64];
    };
    auto MFMA12 = [&](const f16x8 (&A)[6], const f16x8 (&B)[3]) {
        acc0 = __builtin_amdgcn_mfma_f32_16x16x32_f16(A[0], B[0], acc0, 0,0,0);
        acc1 = __builtin_amdgcn_mfma_f32_16x16x32_f16(A[1], B[0], acc1, 0,0,0);
        acc2 = __builtin_amdgcn_mfma_f32_16x16x32_f16(A[2], B[0], acc2, 0,0,0);
        acc3 = __builtin_amdgcn_mfma_f32_16x16x32_f16(A[3], B[0], acc3, 0,0,0);
        acc0 = __builtin_amdgcn_mfma_f32_16x16x32_f16(A[1], B[1], acc0, 0,0,0);
        acc1 = __builtin_amdgcn_mfma_f32_16x16x32_f16(A[2], B[1], acc1, 0,0,0);
        acc2 = __builtin_amdgcn_mfma_f32_16x16x32_f16(A[3], B[1], acc2, 0,0,0);
        acc3 = __builtin_amdgcn_mfma_f32_16x16x32_f16(A[4], B[1], acc3, 0,0,0);
        acc0 = __builtin_amdgcn_mfma_f32_16x16x32_f16(A[2], B[2], acc0, 0,0,0);
        acc1 = __builtin_amdgcn_mfma_f32_16x16x32_f16(A[3], B[2], acc1, 0,0,0);
        acc2 = __builtin_amdgcn_mfma_f32_16x16x32_f16(A[4], B[2], acc2, 0,0,0);
        acc3 = __builtin_amdgcn_mfma_f32_16x16x32_f16(A[5], B[2], acc3, 0,0,0);
    };

    // prologue: pair 0 operands in flight
    LOADA(aX, 0);
    LOADB(bX, 0);

    // 11 pairs (dy 0..21; pair 10's second row hits zero weights)
    #define ST(p, AT, AN, BT, BN)                               \
        do {                                                    \
            if ((p) < 10) { LOADA(AN, (p) + 1); LOADB(BN, (p) + 1); } \
            SBAR();                                             \
            MFMA12(AT, BT);                                     \
            SBAR();                                             \
        } while (0)

    ST( 0, aX, aY, bX, bY); ST( 1, aY, aX, bY, bX);
    ST( 2, aX, aY, bX, bY); ST( 3, aY, aX, bY, bX);
    ST( 4, aX, aY, bX, bY); ST( 5, aY, aX, bY, bX);
    ST( 6, aX, aY, bX, bY); ST( 7, aY, aX, bY, bX);
    ST( 8, aX, aY, bX, bY); ST( 9, aY, aX, bY, bX);
    ST(10, aX, aY, bX, bY);
    #undef ST

    // D layout: lane l, reg q -> row = (l>>4)*4 + q, col = l&15 (dtype-indep)
    const float C = ws[0];
    auto EPI = [&](const f32x4& a4v, const float4& xv, int j) {
        int gx = gxb + 16 * j;
        float cv[4] = {xv.x, xv.y, xv.z, xv.w};
        #pragma unroll
        for (int q = 0; q < 4; ++q) {
            int gy = gy0 + q;
            float a  = cv[q] + C * fmaxf(a4v[q], 0.f);
            float e  = __expf(2.f * fabsf(a));        // tanh(|a|) = 1 - 2/(e+1)
            float r  = 1.f - 2.f * __builtin_amdgcn_rcpf(e + 1.f);
            outp[gy * HW + gx] = copysignf(r, a);
        }
    };
    EPI(acc0, xv0, 0); EPI(acc1, xv1, 1); EPI(acc2, xv2, 2); EPI(acc3, xv3, 3);
}

extern "C" void kernel_launch(void* const* d_in, const int* in_sizes, int n_in,
                              void* d_out, int out_size, void* d_ws, size_t ws_size,
                              hipStream_t stream) {
    const float* x  = (const float*)d_in[0];
    const float* w1 = (const float*)d_in[1];
    const float* w2 = (const float*)d_in[2];
    const float* w3 = (const float*)d_in[3];
    float* out = (float*)d_out;
    float* ws  = (float*)d_ws;

    prep_kernel<<<1, 256, 0, stream>>>(w1, w2, w3, ws);
    copy_kernel<<<2048, 256, 0, stream>>>(x, out);

    dim3 grid(8, 8, 8);      // 512 blocks (64x64 out each) = 2/CU
    dim3 block(256);
    for (int t = 1; t <= NSTEP; ++t)
        step_kernel<<<grid, block, 0, stream>>>(out, out, ws, t);
}